// Round 1
// baseline (519.920 us; speedup 1.0000x reference)
//
#include <hip/hip_runtime.h>
#include <hip/hip_bf16.h>
#include <cstdint>
#include <cstddef>

// Problem constants (B, S, INP, HID) from the reference
#define B_   64
#define S_   2048
#define INP_ 512
#define HID_ 512

typedef float          floatx4  __attribute__((ext_vector_type(4)));
typedef __bf16         bf16x8   __attribute__((ext_vector_type(8)));
typedef unsigned short ushortx8 __attribute__((ext_vector_type(8)));
typedef unsigned short ushortx4 __attribute__((ext_vector_type(4)));

__device__ __forceinline__ unsigned short f2bf(float f) {
  unsigned u = __float_as_uint(f);
  u += 0x7FFFu + ((u >> 16) & 1u);          // round-to-nearest-even
  return (unsigned short)(u >> 16);
}
__device__ __forceinline__ float bf2f(unsigned short h) {
  return __uint_as_float(((unsigned)h) << 16);
}
// tanh(x) = 1 - 2/(exp(2x)+1); exp(2x) = exp2(x * 2*log2(e)).  ~1e-6 accuracy, inf-safe.
__device__ __forceinline__ float fast_tanh(float x) {
  float u = __builtin_amdgcn_exp2f(x * 2.88539008177792681472f);
  return 1.0f - 2.0f * __builtin_amdgcn_rcpf(u + 1.0f);
}

// ---------------------------------------------------------------------------
// Kernel A: hid[b,h] = sum_i inp[b,i]*Wl[h,i] + bl[h]   (tiny fp32 GEMM)
// ---------------------------------------------------------------------------
__global__ void hid_kernel(const float* __restrict__ inp, const float* __restrict__ Wl,
                           const float* __restrict__ bl, float* __restrict__ hid)
{
  __shared__ float ism[512];
  const int b = blockIdx.x, t = threadIdx.x;
  ism[t]       = inp[b * 512 + t];
  ism[t + 256] = inp[b * 512 + 256 + t];
  __syncthreads();
  #pragma unroll
  for (int hh = 0; hh < 2; ++hh) {
    int h = t + hh * 256;
    const float4* wr = (const float4*)(Wl + (size_t)h * 512);
    float4 sv = {0.f, 0.f, 0.f, 0.f};
    for (int i = 0; i < 128; ++i) {
      float4 wv = wr[i];
      float4 iv = *(const float4*)(&ism[i * 4]);
      sv.x += wv.x * iv.x; sv.y += wv.y * iv.y;
      sv.z += wv.z * iv.z; sv.w += wv.w * iv.w;
    }
    hid[b * 512 + h] = bl[h] + sv.x + sv.y + sv.z + sv.w;
  }
}

// ---------------------------------------------------------------------------
// Kernel B: pack Wc (fp32 [HID][INP]) -> bf16 in MFMA A-fragment lane order so
// each A-frag load in the GEMM is one contiguous global_load_dwordx4 per lane.
// Layout: pk[(m16*1024 + ks*64 + lane)*8 + j] = Wc[m16*16 + (lane&15)][ks*32 + (lane>>4)*8 + j]
// ---------------------------------------------------------------------------
__global__ void pack_wc_kernel(const float* __restrict__ Wc, unsigned short* __restrict__ pk)
{
  int g = blockIdx.x * 256 + threadIdx.x;       // 32768 threads
  int l = g & 63, ks = (g >> 6) & 15, m16 = g >> 10;
  int row = m16 * 16 + (l & 15);
  int kb  = ks * 32 + (l >> 4) * 8;
  const float4* s = (const float4*)(Wc + (size_t)row * 512 + kb);
  float4 a = s[0], c = s[1];
  ushortx8 o = { f2bf(a.x), f2bf(a.y), f2bf(a.z), f2bf(a.w),
                 f2bf(c.x), f2bf(c.y), f2bf(c.z), f2bf(c.w) };
  *(ushortx8*)(pk + (size_t)g * 8) = o;
}

// ---------------------------------------------------------------------------
// Kernel C: per (b, s-tile of 64): ctx[h, s] = sum_k Wc[h,k]*context[b,s,k] (+bc)
// via mfma_f32_16x16x32_bf16.  HTILE = 512 (full), 4 waves x 128 h-rows.
// MODE 0: store ctx (bf16) to ws + att partial sums.
// MODE 1: att only (small-ws fallback, pass 1).
// MODE 2: hidden += ctx * alpha (small-ws fallback, pass 2).
// ---------------------------------------------------------------------------
template<int MODE>
__global__ __launch_bounds__(256, 2) void ctx_gemm_kernel(
    const float* __restrict__ context, const unsigned short* __restrict__ Wc_pk,
    const float* __restrict__ hid, const float* __restrict__ bc,
    const float* __restrict__ V,
    unsigned short* __restrict__ ctx_out, float* __restrict__ att,
    const float* __restrict__ alpha, float* __restrict__ hidden)
{
  // context tile: 64 s-rows x 128 k (bf16), XOR-swizzled 16B chunks (<=2-way bank conflicts)
  __shared__ alignas(16) unsigned short bsm[64 * 128];
  __shared__ float hid_sm[512];
  __shared__ float V_sm[512];
  __shared__ float bc_sm[512];
  __shared__ float att_sm[64];
  __shared__ float alpha_sm[64];

  const int b    = blockIdx.y;
  const int s0   = blockIdx.x * 64;
  const int t    = threadIdx.x;
  const int lane = t & 63;
  const int w    = t >> 6;          // wave id: h-rows [w*128, w*128+128)
  const int quad = lane >> 4;
  const int l15  = lane & 15;

  for (int i = t; i < 512; i += 256) {
    hid_sm[i] = hid[b * 512 + i];
    V_sm[i]   = V[i];
    bc_sm[i]  = bc[i];
  }
  if (t < 64) {
    att_sm[t] = 0.0f;
    if (MODE == 2) alpha_sm[t] = alpha[b * S_ + s0 + t];
  }

  floatx4 acc[8][4];
  #pragma unroll
  for (int m = 0; m < 8; ++m)
    #pragma unroll
    for (int n = 0; n < 4; ++n) { floatx4 z = {0.f,0.f,0.f,0.f}; acc[m][n] = z; }

  const unsigned short* apBase = Wc_pk + (size_t)(w * 8) * 8192 + lane * 8;
  const float* src = context + ((size_t)b * S_ + s0) * INP_;

  for (int phase = 0; phase < 4; ++phase) {
    __syncthreads();
    // stage context[b, s0..s0+64)[phase*128 .. +128) -> bf16 LDS, swizzled
    #pragma unroll
    for (int i = 0; i < 8; ++i) {
      int id  = t + i * 256;                  // 0..2047, 32 float4-chunks per row
      int row = id >> 5;
      int c4  = id & 31;
      float4 f = *(const float4*)(src + (size_t)row * INP_ + phase * 128 + c4 * 4);
      int chunk = c4 >> 1, half = c4 & 1;
      int sw = chunk ^ (row & 7);
      ushortx4 hv = { f2bf(f.x), f2bf(f.y), f2bf(f.z), f2bf(f.w) };
      *(ushortx4*)(&bsm[row * 128 + sw * 8 + half * 4]) = hv;
    }
    __syncthreads();
    #pragma unroll
    for (int ksl = 0; ksl < 4; ++ksl) {
      const int ksg = phase * 4 + ksl;
      bf16x8 af[8];
      #pragma unroll
      for (int m = 0; m < 8; ++m)
        af[m] = *(const bf16x8*)(apBase + (size_t)m * 8192 + ksg * 512);
      bf16x8 bfr[4];
      #pragma unroll
      for (int n = 0; n < 4; ++n) {
        int row = n * 16 + l15;
        int c   = ksl * 4 + quad;
        bfr[n] = *(const bf16x8*)(&bsm[row * 128 + ((c ^ (row & 7)) * 8)]);
      }
      #pragma unroll
      for (int m = 0; m < 8; ++m)
        #pragma unroll
        for (int n = 0; n < 4; ++n)
          acc[m][n] = __builtin_amdgcn_mfma_f32_16x16x32_bf16(af[m], bfr[n], acc[m][n], 0, 0, 0);
    }
  }

  // Epilogue.  C/D layout (m89-verified): col(s) = lane&15, row(h) = quad*4 + reg.
  if (MODE == 0 || MODE == 1) {
    float attacc[4] = {0.f, 0.f, 0.f, 0.f};
    #pragma unroll
    for (int m = 0; m < 8; ++m) {
      int hb = w * 128 + m * 16 + quad * 4;
      #pragma unroll
      for (int r = 0; r < 4; ++r) {
        int h = hb + r;
        float bcv = bc_sm[h], hv = hid_sm[h], vv = V_sm[h];
        #pragma unroll
        for (int n = 0; n < 4; ++n) {
          float val = acc[m][n][r] + bcv;
          if (MODE == 0)
            ctx_out[((size_t)b * HID_ + h) * S_ + s0 + n * 16 + l15] = f2bf(val);
          attacc[n] += vv * fast_tanh(hv + val);
        }
      }
    }
    #pragma unroll
    for (int n = 0; n < 4; ++n) {
      float v = attacc[n];
      v += __shfl_xor(v, 16);
      v += __shfl_xor(v, 32);
      if (lane < 16) atomicAdd(&att_sm[n * 16 + l15], v);
    }
    __syncthreads();
    if (t < 64) att[b * S_ + s0 + t] = att_sm[t];
  } else {
    #pragma unroll
    for (int m = 0; m < 8; ++m) {
      int hb = w * 128 + m * 16 + quad * 4;
      #pragma unroll
      for (int r = 0; r < 4; ++r) {
        int h = hb + r;
        float bcv = bc_sm[h];
        float hacc = 0.0f;
        #pragma unroll
        for (int n = 0; n < 4; ++n)
          hacc += (acc[m][n][r] + bcv) * alpha_sm[n * 16 + l15];
        hacc += __shfl_xor(hacc, 1);
        hacc += __shfl_xor(hacc, 2);
        hacc += __shfl_xor(hacc, 4);
        hacc += __shfl_xor(hacc, 8);
        if (l15 == 0) atomicAdd(&hidden[b * HID_ + h], hacc);
      }
    }
  }
}

// ---------------------------------------------------------------------------
// Kernel D: masked softmax over S per batch row.  Auto-detects mask encoding
// (int32 / float32 / packed-uint8) from the first 512 words — in-bounds under
// every interpretation, statistically unambiguous for random 0/1 masks.
// ---------------------------------------------------------------------------
__global__ void softmax_kernel(const void* __restrict__ mask,
                               const float* __restrict__ att,
                               float* __restrict__ alpha)
{
  __shared__ int flags;
  __shared__ float red[8];
  const int b = blockIdx.x, t = threadIdx.x;
  const int lane = t & 63, w = t >> 6;
  if (t == 0) flags = 0;
  __syncthreads();
  int f = 0;
  const unsigned* mw = (const unsigned*)mask;
  for (int i = t; i < 512; i += 256) {
    unsigned v = mw[i];
    if (v > 1u) f |= 1;                               // not plain int32 0/1
    if (v != 0u && v != 0x3f800000u) f |= 2;          // not float32 0.0/1.0
  }
  if (f) atomicOr(&flags, f);
  __syncthreads();
  const int fl = flags;
  const int mode = ((fl & 1) == 0) ? 0 : (((fl & 2) == 0) ? 1 : 2);

  float v[8]; bool msk[8];
  float vmax = -1e30f;
  #pragma unroll
  for (int i = 0; i < 8; ++i) {
    int idx = i * 256 + t;
    bool m;
    if (mode == 0)      m = ((const int*)mask)[b * S_ + idx] != 0;
    else if (mode == 1) m = ((const float*)mask)[b * S_ + idx] != 0.0f;
    else                m = ((const unsigned char*)mask)[b * S_ + idx] != 0;
    msk[i] = m;
    v[i] = att[b * S_ + idx];
    if (!m) vmax = fmaxf(vmax, v[i]);
  }
  #pragma unroll
  for (int off = 32; off; off >>= 1) vmax = fmaxf(vmax, __shfl_xor(vmax, off));
  if (lane == 0) red[w] = vmax;
  __syncthreads();
  vmax = fmaxf(fmaxf(red[0], red[1]), fmaxf(red[2], red[3]));

  float e[8], s = 0.0f;
  #pragma unroll
  for (int i = 0; i < 8; ++i) {
    e[i] = msk[i] ? 0.0f : __builtin_amdgcn_exp2f((v[i] - vmax) * 1.4426950408889634f);
    s += e[i];
  }
  #pragma unroll
  for (int off = 32; off; off >>= 1) s += __shfl_xor(s, off);
  if (lane == 0) red[4 + w] = s;
  __syncthreads();
  s = red[4] + red[5] + red[6] + red[7];
  float rinv = 1.0f / s;
  #pragma unroll
  for (int i = 0; i < 8; ++i)
    alpha[b * S_ + i * 256 + t] = e[i] * rinv;
}

// ---------------------------------------------------------------------------
// Kernel E: hidden[b,h] = sum_s ctx_bf16[b,h,s] * alpha[b,s].  One wave per h.
// ---------------------------------------------------------------------------
__global__ void hidden_kernel(const unsigned short* __restrict__ ctx,
                              const float* __restrict__ alpha,
                              float* __restrict__ hidden)
{
  const int b = blockIdx.y;
  const int w = threadIdx.x >> 6, lane = threadIdx.x & 63;
  const int h = blockIdx.x * 4 + w;
  const unsigned short* cp = ctx + ((size_t)b * HID_ + h) * S_;
  const float* ap = alpha + (size_t)b * S_;
  float acc = 0.0f;
  #pragma unroll
  for (int it = 0; it < 4; ++it) {
    int s = it * 512 + lane * 8;
    ushortx8 cv = *(const ushortx8*)(cp + s);
    float4 a0 = *(const float4*)(ap + s);
    float4 a1 = *(const float4*)(ap + s + 4);
    acc += bf2f(cv[0]) * a0.x + bf2f(cv[1]) * a0.y + bf2f(cv[2]) * a0.z + bf2f(cv[3]) * a0.w
         + bf2f(cv[4]) * a1.x + bf2f(cv[5]) * a1.y + bf2f(cv[6]) * a1.z + bf2f(cv[7]) * a1.w;
  }
  #pragma unroll
  for (int off = 32; off; off >>= 1) acc += __shfl_xor(acc, off);
  if (lane == 0) hidden[b * HID_ + h] = acc;
}

// ---------------------------------------------------------------------------
extern "C" void kernel_launch(void* const* d_in, const int* in_sizes, int n_in,
                              void* d_out, int out_size, void* d_ws, size_t ws_size,
                              hipStream_t stream)
{
  const float* inp     = (const float*)d_in[0];
  const float* context = (const float*)d_in[1];
  const void*  mask    = d_in[2];
  const float* Wl      = (const float*)d_in[3];
  const float* bl      = (const float*)d_in[4];
  const float* Wc      = (const float*)d_in[5];
  const float* bc      = (const float*)d_in[6];
  const float* V       = (const float*)d_in[7];

  float* hidden = (float*)d_out;                 // [B, HID]
  float* alpha  = (float*)d_out + B_ * HID_;     // [B, S]

  char* ws = (char*)d_ws;
  const size_t CTX_BYTES = (size_t)B_ * HID_ * S_ * 2;   // bf16 ctx
  const size_t HIDW_BYTES = (size_t)B_ * HID_ * 4;
  const size_t ATT_BYTES  = (size_t)B_ * S_ * 4;
  const size_t PK_BYTES   = (size_t)HID_ * INP_ * 2;
  const bool big = ws_size >= CTX_BYTES + HIDW_BYTES + ATT_BYTES + PK_BYTES;

  if (big) {
    unsigned short* ctx_bf = (unsigned short*)ws;
    float* hid_ws          = (float*)(ws + CTX_BYTES);
    float* att_ws          = (float*)(ws + CTX_BYTES + HIDW_BYTES);
    unsigned short* pk     = (unsigned short*)(ws + CTX_BYTES + HIDW_BYTES + ATT_BYTES);

    hid_kernel<<<B_, 256, 0, stream>>>(inp, Wl, bl, hid_ws);
    pack_wc_kernel<<<128, 256, 0, stream>>>(Wc, pk);
    ctx_gemm_kernel<0><<<dim3(S_ / 64, B_), 256, 0, stream>>>(
        context, pk, hid_ws, bc, V, ctx_bf, att_ws, nullptr, nullptr);
    softmax_kernel<<<B_, 256, 0, stream>>>(mask, att_ws, alpha);
    hidden_kernel<<<dim3(HID_ / 4, B_), 256, 0, stream>>>(ctx_bf, alpha, hidden);
  } else {
    // small-workspace fallback: recompute the GEMM in pass 2
    float* hid_ws      = (float*)ws;
    float* att_ws      = (float*)(ws + HIDW_BYTES);
    unsigned short* pk = (unsigned short*)(ws + HIDW_BYTES + ATT_BYTES);

    hid_kernel<<<B_, 256, 0, stream>>>(inp, Wl, bl, hid_ws);
    pack_wc_kernel<<<128, 256, 0, stream>>>(Wc, pk);
    ctx_gemm_kernel<1><<<dim3(S_ / 64, B_), 256, 0, stream>>>(
        context, pk, hid_ws, bc, V, nullptr, att_ws, nullptr, nullptr);
    softmax_kernel<<<B_, 256, 0, stream>>>(mask, att_ws, alpha);
    hipMemsetAsync(hidden, 0, HIDW_BYTES, stream);
    ctx_gemm_kernel<2><<<dim3(S_ / 64, B_), 256, 0, stream>>>(
        context, pk, hid_ws, bc, V, nullptr, nullptr, alpha, hidden);
  }
}